// Round 1
// baseline (105.127 us; speedup 1.0000x reference)
//
#include <hip/hip_runtime.h>

#define VDIM   32
#define NPAIR  496      // 32*31/2
#define NBASIS 14       // DEG + ORDER - 1

// One block (256 threads) per row n.
// Phase 1: lanes 0..31 compute the 4 nonzero cubic B-spline weights for x[c].
// Phase 2: each thread writes one float4 of lm[n] (coalesced), accumulating
//          out[n,v] partials reduced via width-8 shuffles.
// Block 0 additionally computes the three penalty scalars.
__global__ __launch_bounds__(256) void Decorrelation_35270271435435_kernel(
    const float* __restrict__ input,    // [N,32]
    const float* __restrict__ params,   // [14,496] row-major (k-major)
    float* __restrict__ out,            // [N,32]
    float* __restrict__ lm,             // [N,32,32]
    float* __restrict__ pens)           // [3]: second_pen, first_pen, param_pen
{
    const int n   = blockIdx.x;
    const int tid = threadIdx.x;

    __shared__ float xin[VDIM];       // raw input (for out = lm @ input)
    __shared__ float wgt[VDIM][4];    // 4 nonzero basis weights per column
    __shared__ int   ibase[VDIM];     // (interval-3)*NPAIR : row offset into params

    if (tid < VDIM) {
        float xi = input[n * VDIM + tid];
        xin[tid] = xi;
        const float LOf  = -15.0f;
        const float HIf  = 15.0f;
        const float EPSf = 1e-6f;
        const float dist = 30.0f / 11.0f;          // (HI-LO)/(DEG-1)
        const float invd = 11.0f / 30.0f;
        const float t0   = LOf - 3.0f * dist;      // knots[0]
        float x = fminf(fmaxf(xi, LOf), HIf - EPSf);
        float u = (x - t0) * invd;                 // knot-units from knots[0]
        int   i = (int)floorf(u);
        i = min(13, max(3, i));                    // valid interval range
        float uu  = u - (float)i;                  // local coord in [0,1)
        float om  = 1.0f - uu;
        float uu2 = uu * uu, uu3 = uu2 * uu;
        const float sixth = 1.0f / 6.0f;
        wgt[tid][0] = om * om * om * sixth;                                // N_{i-3}
        wgt[tid][1] = (3.0f * uu3 - 6.0f * uu2 + 4.0f) * sixth;            // N_{i-2}
        wgt[tid][2] = (-3.0f * uu3 + 3.0f * uu2 + 3.0f * uu + 1.0f) * sixth; // N_{i-1}
        wgt[tid][3] = uu3 * sixth;                                         // N_{i}
        ibase[tid]  = (i - 3) * NPAIR;
    }
    __syncthreads();

    // Each thread: 4 consecutive elements of lm[n] -> row v, cols c0..c0+3.
    const int v  = tid >> 3;
    const int c0 = (tid & 7) << 2;
    float vals[4];
    float partial = 0.0f;
    #pragma unroll
    for (int j = 0; j < 4; ++j) {
        const int c = c0 + j;
        float val;
        if (c == v) {
            val = 1.0f;                 // unit diagonal
        } else if (c < v) {
            const int p = (v * (v - 1)) / 2 + c;   // tril_indices(-1) flat order
            const int b = ibase[c] + p;
            val = wgt[c][0] * params[b]
                + wgt[c][1] * params[b + NPAIR]
                + wgt[c][2] * params[b + 2 * NPAIR]
                + wgt[c][3] * params[b + 3 * NPAIR];
        } else {
            val = 0.0f;                 // strict upper
        }
        vals[j] = val;
        partial += val * xin[c];
    }
    float4 f4 = make_float4(vals[0], vals[1], vals[2], vals[3]);
    *(float4*)(lm + (size_t)n * (VDIM * VDIM) + tid * 4) = f4;

    // out[n,v] = sum over this row's 32 cols; 8 threads share a row (width-8).
    partial += __shfl_down(partial, 4, 8);
    partial += __shfl_down(partial, 2, 8);
    partial += __shfl_down(partial, 1, 8);
    if ((tid & 7) == 0) out[n * VDIM + v] = partial;

    // Penalty scalars: fused into block 0 (params is only 14*496 = 6944 floats).
    if (blockIdx.x == 0) {
        float s2 = 0.0f, s1 = 0.0f, sp = 0.0f;
        const int NP = NBASIS * NPAIR;  // 6944
        for (int idx = tid; idx < NP; idx += 256) {
            const float a = params[idx];
            sp += a * a;
            if (idx < NP - NPAIR) {
                const float b = params[idx + NPAIR];      // next k, same p
                const float d1 = b - a;
                s1 += d1 * d1;
                if (idx < NP - 2 * NPAIR) {
                    const float c = params[idx + 2 * NPAIR];
                    const float d2 = c - 2.0f * b + a;
                    s2 += d2 * d2;
                }
            }
        }
        #pragma unroll
        for (int off = 32; off > 0; off >>= 1) {
            s2 += __shfl_down(s2, off);
            s1 += __shfl_down(s1, off);
            sp += __shfl_down(sp, off);
        }
        __shared__ float wsum[3][4];
        const int lane = tid & 63, wid = tid >> 6;
        if (lane == 0) { wsum[0][wid] = s2; wsum[1][wid] = s1; wsum[2][wid] = sp; }
        __syncthreads();
        if (tid == 0) {
            pens[0] = wsum[0][0] + wsum[0][1] + wsum[0][2] + wsum[0][3]; // second_pen
            pens[1] = wsum[1][0] + wsum[1][1] + wsum[1][2] + wsum[1][3]; // first_pen
            pens[2] = wsum[2][0] + wsum[2][1] + wsum[2][2] + wsum[2][3]; // param_pen
        }
    }
}

extern "C" void kernel_launch(void* const* d_in, const int* in_sizes, int n_in,
                              void* d_out, int out_size, void* d_ws, size_t ws_size,
                              hipStream_t stream) {
    const float* input  = (const float*)d_in[0];   // [N,32]
    // d_in[1] = log_d : unused by the reference computation
    const float* params = (const float*)d_in[2];   // [14,496]
    const int N = in_sizes[0] / VDIM;              // 16384

    float* out  = (float*)d_out;                   // [N,32]
    float* lm   = out + (size_t)N * VDIM;          // [N,32,32]
    float* pens = lm + (size_t)N * VDIM * VDIM;    // [3]

    Decorrelation_35270271435435_kernel<<<N, 256, 0, stream>>>(input, params, out, lm, pens);
}

// Round 2
// 93.990 us; speedup vs baseline: 1.1185x; 1.1185x over previous
//
#include <hip/hip_runtime.h>

#define VDIM   32
#define NPAIR  496              // 32*31/2
#define NBASIS 14               // DEG + ORDER - 1
#define NPARAM (NBASIS * NPAIR) // 6944
#define ROWS   16               // rows per block

typedef float f32x4 __attribute__((ext_vector_type(4)));

// 1024 blocks x 256 threads; each block: stage params->LDS once, then emit
// 16 rows of lm (coalesced float4 nontemporal stores) + out via shuffles.
__global__ __launch_bounds__(256) void Decorrelation_35270271435435_kernel(
    const float* __restrict__ input,    // [N,32]
    const float* __restrict__ params,   // [14,496] k-major
    float* __restrict__ out,            // [N,32]
    float* __restrict__ lm,             // [N,32,32]
    float* __restrict__ pens,           // [3]
    int N)
{
    __shared__ float sp[NPARAM];             // 27.8 KB staged params
    __shared__ float xin[ROWS][VDIM];        // raw inputs (for out = lm@x)
    __shared__ float wgt[4][ROWS][VDIM];     // t-major: row-loop reads are bank-broadcast
    __shared__ int   ib [ROWS][VDIM];        // (interval-3)*NPAIR per (row,col)

    const int tid = threadIdx.x;
    const int n0  = blockIdx.x * ROWS;

    // ---- Stage params into LDS (coalesced float4; 1736 vec4s / 256 thr) ----
    {
        const f32x4* p4 = (const f32x4*)params;
        f32x4*       s4 = (f32x4*)sp;
        for (int i = tid; i < NPARAM / 4; i += 256) s4[i] = p4[i];
    }

    // ---- Inputs + cubic B-spline weights: 512 items, 2 per thread ----
    #pragma unroll
    for (int it = 0; it < 2; ++it) {
        const int item = tid + it * 256;
        const int r = item >> 5, c = item & 31;
        const int n = n0 + r;
        const float xi = (n < N) ? input[n * VDIM + c] : 0.0f;
        xin[r][c] = xi;
        const float dist = 30.0f / 11.0f;      // (HI-LO)/(DEG-1)
        const float invd = 11.0f / 30.0f;
        const float t0   = -15.0f - 3.0f * dist;
        float x = fminf(fmaxf(xi, -15.0f), 15.0f - 1e-6f);
        float u = (x - t0) * invd;
        int   i = (int)floorf(u);
        i = min(13, max(3, i));
        const float uu  = u - (float)i;
        const float om  = 1.0f - uu;
        const float uu2 = uu * uu, uu3 = uu2 * uu;
        const float sixth = 1.0f / 6.0f;
        wgt[0][r][c] = om * om * om * sixth;
        wgt[1][r][c] = (3.0f * uu3 - 6.0f * uu2 + 4.0f) * sixth;
        wgt[2][r][c] = (-3.0f * uu3 + 3.0f * uu2 + 3.0f * uu + 1.0f) * sixth;
        wgt[3][r][c] = uu3 * sixth;
        ib[r][c] = (i - 3) * NPAIR;
    }
    __syncthreads();

    // ---- Per-thread constants (invariant across the 16 rows) ----
    const int v  = tid >> 3;          // lm row this thread serves
    const int c0 = (tid & 7) << 2;    // first of 4 consecutive cols
    int  pidx[4];
    bool low[4], dia[4];
    #pragma unroll
    for (int j = 0; j < 4; ++j) {
        const int c = c0 + j;
        low[j]  = (c < v);
        dia[j]  = (c == v);
        pidx[j] = (v * (v - 1)) / 2 + c;   // tril_indices(-1) flat order
    }

    float* lmp = lm + (size_t)n0 * (VDIM * VDIM) + tid * 4;

    for (int r = 0; r < ROWS; ++r, lmp += VDIM * VDIM) {
        const int n = n0 + r;
        if (n >= N) break;
        float vals[4];
        float partial = 0.0f;
        #pragma unroll
        for (int j = 0; j < 4; ++j) {
            const int c = c0 + j;
            float val;
            if (dia[j]) {
                val = 1.0f;
            } else if (low[j]) {
                const int b = ib[r][c] + pidx[j];
                val = wgt[0][r][c] * sp[b]
                    + wgt[1][r][c] * sp[b + NPAIR]
                    + wgt[2][r][c] * sp[b + 2 * NPAIR]
                    + wgt[3][r][c] * sp[b + 3 * NPAIR];
            } else {
                val = 0.0f;
            }
            vals[j] = val;
            partial += val * xin[r][c];
        }
        f32x4 f4 = { vals[0], vals[1], vals[2], vals[3] };
        __builtin_nontemporal_store(f4, (f32x4*)lmp);

        partial += __shfl_down(partial, 4, 8);
        partial += __shfl_down(partial, 2, 8);
        partial += __shfl_down(partial, 1, 8);
        if ((tid & 7) == 0) out[n * VDIM + v] = partial;
    }

    // ---- Penalty scalars (block 0 only; reads the LDS params copy) ----
    if (blockIdx.x == 0) {
        float s2 = 0.0f, s1 = 0.0f, spn = 0.0f;
        for (int idx = tid; idx < NPARAM; idx += 256) {
            const float a = sp[idx];
            spn += a * a;
            if (idx < NPARAM - NPAIR) {
                const float b = sp[idx + NPAIR];
                const float d1 = b - a;
                s1 += d1 * d1;
                if (idx < NPARAM - 2 * NPAIR) {
                    const float c = sp[idx + 2 * NPAIR];
                    const float d2 = c - 2.0f * b + a;
                    s2 += d2 * d2;
                }
            }
        }
        #pragma unroll
        for (int off = 32; off > 0; off >>= 1) {
            s2  += __shfl_down(s2, off);
            s1  += __shfl_down(s1, off);
            spn += __shfl_down(spn, off);
        }
        __shared__ float wsum[3][4];
        const int lane = tid & 63, wid = tid >> 6;
        if (lane == 0) { wsum[0][wid] = s2; wsum[1][wid] = s1; wsum[2][wid] = spn; }
        __syncthreads();
        if (tid == 0) {
            pens[0] = wsum[0][0] + wsum[0][1] + wsum[0][2] + wsum[0][3];
            pens[1] = wsum[1][0] + wsum[1][1] + wsum[1][2] + wsum[1][3];
            pens[2] = wsum[2][0] + wsum[2][1] + wsum[2][2] + wsum[2][3];
        }
    }
}

extern "C" void kernel_launch(void* const* d_in, const int* in_sizes, int n_in,
                              void* d_out, int out_size, void* d_ws, size_t ws_size,
                              hipStream_t stream) {
    const float* input  = (const float*)d_in[0];   // [N,32]
    // d_in[1] = log_d : unused by the reference
    const float* params = (const float*)d_in[2];   // [14,496]
    const int N = in_sizes[0] / VDIM;              // 16384

    float* out  = (float*)d_out;                   // [N,32]
    float* lm   = out + (size_t)N * VDIM;          // [N,32,32]
    float* pens = lm + (size_t)N * VDIM * VDIM;    // [3]

    const int nb = (N + ROWS - 1) / ROWS;          // 1024
    Decorrelation_35270271435435_kernel<<<nb, 256, 0, stream>>>(
        input, params, out, lm, pens, N);
}